// Round 1
// baseline (507.346 us; speedup 1.0000x reference)
//
#include <hip/hip_runtime.h>
#include <math.h>

// Problem constants (B=4, S=4096, H=4096, E=64, top_k=8)
#define H_DIM  4096
#define E_NUM  64
#define N_TOK  16384          // B*S
#define TPB    64             // tokens per block
#define KC     64             // K chunk
#define NCHUNK (H_DIM / KC)   // 64
#define TOPK   8

// flat output layout: [probs (N_TOK*64)][indices (N_TOK*8)][gate (N_TOK*64)]
#define N_PROBS  (N_TOK * E_NUM)          // 1048576
#define N_IDX    (N_TOK * TOPK)           // 131072
#define OFF_IDX  N_PROBS
#define OFF_GATE (N_PROBS + N_IDX)        // 1179648

// v2: 512-thread blocks; the two 256-thread halves (groups) split each K-chunk
// (group g computes k in [32g, 32g+32)). This doubles waves/SIMD from 1 to 2 so
// ds_read latency + the sstore/barrier tail of one wave hides under the other
// wave's FMA stream. Load/store/LDS-read paths are identical to the verified
// 453us kernel. fp64 partials are reduced across groups through LDS at the end.
__global__ __launch_bounds__(512, 2)
void gating_kernel(const float* __restrict__ x, const float* __restrict__ W,
                   float* __restrict__ out) {
  // LDS: k-major double-buffered tiles (same as before, 64 KB total), unioned
  // with (a) the cross-group fp64 reduction dump (overlays the dead ws region)
  // and (b) the epilogue logits scratch (overlays the dead xs region).
  __shared__ union {
    struct { float xs[2][KC][TPB]; float ws[2][KC][E_NUM]; } t; // 32 KB + 32 KB
    struct { float pad[8192]; double b[16][256]; } r;           // dump @ +32 KB
    float lg[TPB][E_NUM + 1];   // 16.6 KB, stride 65 breaks phase-2 conflicts
  } u;

  const int tid  = threadIdx.x;
  const int g    = tid >> 8;    // K-half group: 0 -> k<32 of chunk, 1 -> k>=32
  const int gtid = tid & 255;
  const int tok0 = blockIdx.x * TPB;
  const int tx   = gtid & 15;   // expert group: experts 4*tx..4*tx+3
  const int ty   = gtid >> 4;   // token group:  tokens 4*ty..4*ty+3

  const float* xg = x + (size_t)tok0 * H_DIM;

  float4 xr[2], wr[2];

  // 64x64 tile load across all 512 threads: f4 = tid+512p -> row = f4&63,
  // kq = f4>>6. Per wave: 64 rows x 16 B (L1 absorbs across passes).
  auto gload = [&](int kb) {
#pragma unroll
    for (int p = 0; p < 2; ++p) {
      const int f4  = tid + 512 * p;
      const int row = f4 & 63;
      const int kq  = f4 >> 6;
      xr[p] = *(const float4*)(xg + row * H_DIM + kb + 4 * kq);
      wr[p] = *(const float4*)(W  + row * H_DIM + kb + 4 * kq);
    }
  };
  // transposed store into k-major LDS tiles (scalar writes, 2-way banks = free)
  auto sstore = [&](int b) {
#pragma unroll
    for (int p = 0; p < 2; ++p) {
      const int f4  = tid + 512 * p;
      const int row = f4 & 63;
      const int k0  = (f4 >> 6) << 2;
      u.t.xs[b][k0 + 0][row] = xr[p].x;
      u.t.xs[b][k0 + 1][row] = xr[p].y;
      u.t.xs[b][k0 + 2][row] = xr[p].z;
      u.t.xs[b][k0 + 3][row] = xr[p].w;
      u.t.ws[b][k0 + 0][row] = wr[p].x;
      u.t.ws[b][k0 + 1][row] = wr[p].y;
      u.t.ws[b][k0 + 2][row] = wr[p].z;
      u.t.ws[b][k0 + 3][row] = wr[p].w;
    }
  };

  gload(0);
  sstore(0);
  __syncthreads();

  // Precision: fp32 accumulation spans exactly 64 products (2 chunks x 32 k)
  // before the fp64 fold -> identical error structure to the verified kernel,
  // so the top-8 ranking vs the fp32 reference is preserved.
  double accd[4][4];
  float  ca[4][4];
#pragma unroll
  for (int i = 0; i < 4; ++i)
#pragma unroll
    for (int j = 0; j < 4; ++j) { accd[i][j] = 0.0; ca[i][j] = 0.f; }

  for (int c = 0; c < NCHUNK; ++c) {
    if (c + 1 < NCHUNK) gload((c + 1) * KC);   // prefetch next chunk to regs
    const int b = c & 1;

#pragma unroll 8
    for (int kk = 0; kk < KC / 2; ++kk) {
      const int k = (g << 5) | kk;             // this group's K-half
      const float4 av = *(const float4*)&u.t.xs[b][k][4 * ty];
      const float4 bv = *(const float4*)&u.t.ws[b][k][4 * tx];
      const float a[4]  = {av.x, av.y, av.z, av.w};
      const float bb[4] = {bv.x, bv.y, bv.z, bv.w};
#pragma unroll
      for (int i = 0; i < 4; ++i)
#pragma unroll
        for (int j = 0; j < 4; ++j)
          ca[i][j] = fmaf(a[i], bb[j], ca[i][j]);
    }

    if (c & 1) {   // fold every 2 chunks = every 64 fp32 products
#pragma unroll
      for (int i = 0; i < 4; ++i)
#pragma unroll
        for (int j = 0; j < 4; ++j) {
          accd[i][j] += (double)ca[i][j];
          ca[i][j] = 0.f;
        }
    }

    if (c + 1 < NCHUNK) {
      // writes go to buffer (c+1)&1, whose last readers finished before the
      // barrier that ended iteration c-1 -> one barrier per chunk suffices.
      sstore((c + 1) & 1);
      __syncthreads();
    }
  }
  __syncthreads();   // all compute done before the dump overlays ws

  // cross-group fp64 reduce: group 1 dumps, group 0 adds.
  // [16][256] layout -> consecutive lanes write/read stride-2 words = 2-way free.
  if (g == 1) {
#pragma unroll
    for (int i = 0; i < 4; ++i)
#pragma unroll
      for (int j = 0; j < 4; ++j)
        u.r.b[4 * i + j][gtid] = accd[i][j];
  }
  __syncthreads();

  float acc[4][4];
  if (g == 0) {
#pragma unroll
    for (int i = 0; i < 4; ++i)
#pragma unroll
      for (int j = 0; j < 4; ++j)
        acc[i][j] = (float)(accd[i][j] + u.r.b[4 * i + j][gtid]);

    // gate_logit: coalesced float4 stores (registers -> global)
    float* gate = out + OFF_GATE;
#pragma unroll
    for (int i = 0; i < 4; ++i) {
      const int t = 4 * ty + i;
      float4 v = make_float4(acc[i][0], acc[i][1], acc[i][2], acc[i][3]);
      *(float4*)(gate + (size_t)(tok0 + t) * E_NUM + 4 * tx) = v;
    }

    // stage logits for the epilogue (lg overlays dead xs region; r.b untouched)
#pragma unroll
    for (int i = 0; i < 4; ++i)
#pragma unroll
      for (int j = 0; j < 4; ++j)
        u.lg[4 * ty + i][4 * tx + j] = acc[i][j];
  }
  __syncthreads();

  // Phase 2: one thread per token (wave 0 only; epilogue is ~2% of runtime).
  if (tid < TPB) {
    const int t = tid;
    float vals[TOPK];
    int   idxs[TOPK];
#pragma unroll
    for (int p = 0; p < TOPK; ++p) {
      float best = -INFINITY;
      int   bi   = 0;
      for (int e = 0; e < E_NUM; ++e) {
        const float v = u.lg[t][e];
        if (v > best) { best = v; bi = e; }   // strict > == jax lowest-index tie-break
      }
      vals[p] = best;
      idxs[p] = bi;
      u.lg[t][bi] = -INFINITY;
    }
    // softmax over the selected 8 (masked softmax: others are exactly 0)
    const float m = vals[0];
    float s = 0.f, pr[TOPK];
#pragma unroll
    for (int p = 0; p < TOPK; ++p) { pr[p] = __expf(vals[p] - m); s += pr[p]; }
    const float inv = 1.0f / s;
    for (int e = 0; e < E_NUM; ++e) u.lg[t][e] = 0.f;
#pragma unroll
    for (int p = 0; p < TOPK; ++p) u.lg[t][idxs[p]] = pr[p] * inv;

    // indices: flat out buffer is fp32 -> write as float (exact for 0..63)
    float* oidx = out + OFF_IDX + (size_t)(tok0 + t) * TOPK;
#pragma unroll
    for (int p = 0; p < TOPK; ++p) oidx[p] = (float)idxs[p];
  }
  __syncthreads();

  // coalesced writeback of the sparse_probs rows (all 512 threads)
  float* oprob = out + (size_t)tok0 * E_NUM;
#pragma unroll
  for (int p = 0; p < 8; ++p) {
    const int f = tid + 512 * p;
    oprob[f] = u.lg[f >> 6][f & 63];
  }
}

extern "C" void kernel_launch(void* const* d_in, const int* in_sizes, int n_in,
                              void* d_out, int out_size, void* d_ws, size_t ws_size,
                              hipStream_t stream) {
  const float* x = (const float*)d_in[0];
  const float* W = (const float*)d_in[1];
  float* out = (float*)d_out;
  dim3 grid(N_TOK / TPB);   // 256 blocks -> 1 per CU
  dim3 block(512);          // 8 waves -> 2 waves/SIMD
  gating_kernel<<<grid, block, 0, stream>>>(x, W, out);
}

// Round 2
// 466.482 us; speedup vs baseline: 1.0876x; 1.0876x over previous
//
#include <hip/hip_runtime.h>
#include <math.h>

// Problem constants (B=4, S=4096, H=4096, E=64, top_k=8)
#define H_DIM   4096
#define E_NUM   64
#define N_TOK   16384         // B*S
#define TOPK    8

// v3: K-split-2 GEMM with fat 8x4 register tiles at 1 wave/SIMD.
// v2 post-mortem: 2 waves/SIMD with 2.0 B/FMA LDS traffic exploded
// SQ_LDS_BANK_CONFLICT 117K -> 33.6M (= +55us, the whole regression).
// So: stay at 4 waves/block (conflict-free regime), cut LDS bytes/FMA
// 2.0 -> 1.5 via 8-token x 4-expert tiles. 128 tokens/block x 2 K-halves
// = 256 blocks = 1/CU. Partials (fp32) park in the gate/probs output
// regions; kernel2 sums them (error ~1e-7, same class as v1's fp64
// folds -> top-8 ranking preserved) and runs the v1 epilogue verbatim.
#define TPB1    128           // tokens per gemm block
#define KSPLIT  2
#define KHALF   (H_DIM / KSPLIT)   // 2048
#define KC      64            // K chunk
#define NCHUNK1 (KHALF / KC)  // 32

// flat output layout: [probs (N_TOK*64)][indices (N_TOK*8)][gate (N_TOK*64)]
#define N_PROBS  (N_TOK * E_NUM)          // 1048576
#define N_IDX    (N_TOK * TOPK)           // 131072
#define OFF_IDX  N_PROBS
#define OFF_GATE (N_PROBS + N_IDX)        // 1179648

__global__ __launch_bounds__(256, 1)
void gemm_part(const float* __restrict__ x, const float* __restrict__ W,
               float* __restrict__ out) {
  // k-major tiles, double-buffered. xs rows are 128 floats (4x32 banks):
  // transposed scalar stores hit bank lane&31 (2-way = free), b128 fragment
  // reads are broadcast/row-contiguous (conflict-free). 96 KB total.
  __shared__ float xs[2][KC][TPB1];   // 64 KB  [buf][k][token]
  __shared__ float ws[2][KC][E_NUM];  // 32 KB  [buf][k][expert]

  const int tid    = threadIdx.x;
  const int tokgrp = blockIdx.x >> 1;
  const int kpart  = blockIdx.x & 1;      // which K half
  const int tok0   = tokgrp * TPB1;
  const int tx     = tid & 15;            // experts 4*tx..4*tx+3
  const int ty     = tid >> 4;            // tokens  8*ty..8*ty+7  (ty in 0..15)

  const float* xg = x + (size_t)tok0 * H_DIM + (size_t)kpart * KHALF;
  const float* wg = W + (size_t)kpart * KHALF;

  float4 xr[8], wr[4];

  // x tile: 64k x 128tok = 2048 float4; w tile: 64k x 64exp = 1024 float4.
  // Per wave-pass: 64 consecutive rows x 16 B (L1/L2/L3 absorb re-reads).
  auto gload = [&](int kb) {
#pragma unroll
    for (int p = 0; p < 8; ++p) {
      const int f4  = tid + 256 * p;
      const int row = f4 & 127;           // token
      const int kq  = f4 >> 7;            // k quad (0..15)
      xr[p] = *(const float4*)(xg + (size_t)row * H_DIM + kb + 4 * kq);
    }
#pragma unroll
    for (int p = 0; p < 4; ++p) {
      const int f4  = tid + 256 * p;
      const int row = f4 & 63;            // expert
      const int kq  = f4 >> 6;            // k quad (0..15)
      wr[p] = *(const float4*)(wg + (size_t)row * H_DIM + kb + 4 * kq);
    }
  };
  // transposed store into k-major tiles (scalar writes, bank = lane&31, free)
  auto sstore = [&](int b) {
#pragma unroll
    for (int p = 0; p < 8; ++p) {
      const int f4  = tid + 256 * p;
      const int row = f4 & 127;
      const int k0  = (f4 >> 7) << 2;
      xs[b][k0 + 0][row] = xr[p].x;
      xs[b][k0 + 1][row] = xr[p].y;
      xs[b][k0 + 2][row] = xr[p].z;
      xs[b][k0 + 3][row] = xr[p].w;
    }
#pragma unroll
    for (int p = 0; p < 4; ++p) {
      const int f4  = tid + 256 * p;
      const int row = f4 & 63;
      const int k0  = (f4 >> 6) << 2;
      ws[b][k0 + 0][row] = wr[p].x;
      ws[b][k0 + 1][row] = wr[p].y;
      ws[b][k0 + 2][row] = wr[p].z;
      ws[b][k0 + 3][row] = wr[p].w;
    }
  };

  gload(0);
  sstore(0);
  __syncthreads();

  // Precision: fp32 chains of exactly 64 products (one chunk) then fp64 fold,
  // identical error structure to the verified 453us kernel (~2e-7 vs fp32 ref).
  double accd[8][4];
  float  ca[8][4];
#pragma unroll
  for (int i = 0; i < 8; ++i)
#pragma unroll
    for (int j = 0; j < 4; ++j) { accd[i][j] = 0.0; ca[i][j] = 0.f; }

  for (int c = 0; c < NCHUNK1; ++c) {
    if (c + 1 < NCHUNK1) gload((c + 1) * KC);   // prefetch next chunk to regs
    const int b = c & 1;

#pragma unroll 4
    for (int k = 0; k < KC; ++k) {
      const float4 a0 = *(const float4*)&xs[b][k][8 * ty];
      const float4 a1 = *(const float4*)&xs[b][k][8 * ty + 4];
      const float4 bv = *(const float4*)&ws[b][k][4 * tx];
      const float a[8]  = {a0.x, a0.y, a0.z, a0.w, a1.x, a1.y, a1.z, a1.w};
      const float bb[4] = {bv.x, bv.y, bv.z, bv.w};
#pragma unroll
      for (int i = 0; i < 8; ++i)
#pragma unroll
        for (int j = 0; j < 4; ++j)
          ca[i][j] = fmaf(a[i], bb[j], ca[i][j]);
    }
#pragma unroll
    for (int i = 0; i < 8; ++i)
#pragma unroll
      for (int j = 0; j < 4; ++j) { accd[i][j] += (double)ca[i][j]; ca[i][j] = 0.f; }

    if (c + 1 < NCHUNK1) {
      // writes target buffer (c+1)&1 whose last readers finished before the
      // barrier that ended iteration c-1 -> one barrier per chunk suffices.
      sstore((c + 1) & 1);
      __syncthreads();
    }
  }

  // partial logits, fp32 (rounding ~4e-8, inside the 2e-7 budget):
  // K-half 0 -> gate region, K-half 1 -> probs region. Coalesced float4.
  float* pout = out + (kpart ? 0 : OFF_GATE);
#pragma unroll
  for (int i = 0; i < 8; ++i) {
    const int t = 8 * ty + i;
    float4 v = make_float4((float)accd[i][0], (float)accd[i][1],
                           (float)accd[i][2], (float)accd[i][3]);
    *(float4*)(pout + (size_t)(tok0 + t) * E_NUM + 4 * tx) = v;
  }
}

// Kernel 2: sum the two partials, write gate, top-k + masked softmax + probs.
// 256 blocks x 64 tokens; epilogue logic identical to the verified kernel.
__global__ __launch_bounds__(256, 1)
void reduce_epilogue(float* __restrict__ out) {
  __shared__ float lg[64][E_NUM + 1];   // stride 65 breaks phase-2 conflicts

  const int tid  = threadIdx.x;
  const int tok0 = blockIdx.x * 64;
  const int tx   = tid & 15;            // experts 4*tx..4*tx+3
  const int ty   = tid >> 4;            // tokens  4*ty..4*ty+3

  float* gate = out + OFF_GATE;         // holds partial A, becomes gate output
  float* prob = out;                    // holds partial B, becomes probs output

  // read both partials (coalesced f4), sum, write gate, stage logits in LDS
#pragma unroll
  for (int i = 0; i < 4; ++i) {
    const int t = 4 * ty + i;
    const size_t off = (size_t)(tok0 + t) * E_NUM + 4 * tx;
    const float4 pa = *(const float4*)(gate + off);
    const float4 pb = *(const float4*)(prob + off);
    float4 v = make_float4(pa.x + pb.x, pa.y + pb.y, pa.z + pb.z, pa.w + pb.w);
    *(float4*)(gate + off) = v;
    lg[t][4 * tx + 0] = v.x;
    lg[t][4 * tx + 1] = v.y;
    lg[t][4 * tx + 2] = v.z;
    lg[t][4 * tx + 3] = v.w;
  }
  __syncthreads();

  // Phase 2: one thread per token (wave 0 only).
  if (tid < 64) {
    const int t = tid;
    float vals[TOPK];
    int   idxs[TOPK];
#pragma unroll
    for (int p = 0; p < TOPK; ++p) {
      float best = -INFINITY;
      int   bi   = 0;
      for (int e = 0; e < E_NUM; ++e) {
        const float v = lg[t][e];
        if (v > best) { best = v; bi = e; }   // strict > == jax lowest-index tie-break
      }
      vals[p] = best;
      idxs[p] = bi;
      lg[t][bi] = -INFINITY;
    }
    // softmax over the selected 8 (masked softmax: others are exactly 0)
    const float m = vals[0];
    float s = 0.f, pr[TOPK];
#pragma unroll
    for (int p = 0; p < TOPK; ++p) { pr[p] = __expf(vals[p] - m); s += pr[p]; }
    const float inv = 1.0f / s;
    for (int e = 0; e < E_NUM; ++e) lg[t][e] = 0.f;
#pragma unroll
    for (int p = 0; p < TOPK; ++p) lg[t][idxs[p]] = pr[p] * inv;

    // indices: flat out buffer is fp32 -> write as float (exact for 0..63)
    float* oidx = out + OFF_IDX + (size_t)(tok0 + t) * TOPK;
#pragma unroll
    for (int p = 0; p < TOPK; ++p) oidx[p] = (float)idxs[p];
  }
  __syncthreads();

  // coalesced writeback of the sparse_probs rows (overwrites partial B)
  float* oprob = prob + (size_t)tok0 * E_NUM;
#pragma unroll
  for (int p = 0; p < 16; ++p) {
    const int f = tid + 256 * p;
    oprob[f] = lg[f >> 6][f & 63];
  }
}

extern "C" void kernel_launch(void* const* d_in, const int* in_sizes, int n_in,
                              void* d_out, int out_size, void* d_ws, size_t ws_size,
                              hipStream_t stream) {
  const float* x = (const float*)d_in[0];
  const float* W = (const float*)d_in[1];
  float* out = (float*)d_out;
  // 128 token groups x 2 K-halves = 256 blocks -> 1 per CU
  gemm_part<<<dim3(N_TOK / TPB1 * KSPLIT), dim3(256), 0, stream>>>(x, W, out);
  reduce_epilogue<<<dim3(N_TOK / 64), dim3(256), 0, stream>>>(out);
}

// Round 3
// 405.888 us; speedup vs baseline: 1.2500x; 1.1493x over previous
//
#include <hip/hip_runtime.h>
#include <math.h>

// Problem constants (B=4, S=4096, H=4096, E=64, top_k=8)
#define H_DIM  4096
#define E_NUM  64
#define N_TOK  16384          // B*S
#define TPB    64             // tokens per block
#define KC     64             // K chunk
#define NCHUNK (H_DIM / KC)   // 64
#define TOPK   8

// flat output layout: [probs (N_TOK*64)][indices (N_TOK*8)][gate (N_TOK*64)]
#define N_PROBS  (N_TOK * E_NUM)          // 1048576
#define N_IDX    (N_TOK * TOPK)           // 131072
#define OFF_IDX  N_PROBS
#define OFF_GATE (N_PROBS + N_IDX)        // 1179648

// v4: MFMA path. fp32 = hi+mid+lo (3x RNE bf16, exact to 2^-24). Logits via
// 6 bf16 MFMA products (hh,hm,mh,mm,hl,lh) on v_mfma_f32_32x32x16_bf16.
// v1-v3 post-mortem: fp32-VALU version is latency-bound at 1 wave/SIMD
// (per-group read-wait + FMA chain = measured time), VALU floor ~55us
// unreachable; MFMA floor is 25us and MfmaUtil was 0. Error budget ~2.5e-7
// (product terms 2^-24-class; fp32 acc chains <=96 adds between fp64 folds;
// dropped ml/ll terms ~6e-8) = same class as the verified 453us kernel.
#define XH 0
#define XM 1
#define XL 2
#define WH 3
#define WM 4
#define WL 5

typedef __attribute__((ext_vector_type(8)))  short short8;   // 8 bf16 = 4 VGPR
typedef __attribute__((ext_vector_type(16))) float f32x16;   // 32x32 acc

// RNE fp32 -> bf16, returning the bf16 bits and the exact fp32 remainder.
__device__ __forceinline__ unsigned short bf_split(float v, float& rem) {
  unsigned u  = __builtin_bit_cast(unsigned, v);
  unsigned hb = (u + 0x7FFFu + ((u >> 16) & 1u)) & 0xFFFF0000u;
  rem = v - __builtin_bit_cast(float, hb);   // exact (Sterbenz: same binade)
  return (unsigned short)(hb >> 16);
}
__device__ __forceinline__ unsigned short bf_rne(float v) {
  unsigned u = __builtin_bit_cast(unsigned, v);
  return (unsigned short)((u + 0x7FFFu + ((u >> 16) & 1u)) >> 16);
}

__global__ __launch_bounds__(256, 1)
void gating_kernel(const float* __restrict__ x, const float* __restrict__ W,
                   float* __restrict__ out) {
  // 6 bf16 tiles [64 rows][64 k], double-buffered = 96 KB. Row = 128 B, so
  // un-swizzled b128 frag reads would be 16-way bank conflicts (G4); XOR
  // byte ^= (row&7)<<4 spreads them (reads ~2-way = free, b64 stores 4-way).
  // lg overlays the tiles after the GEMM for the epilogue.
  __shared__ union {
    unsigned short tiles[2][6][64][64];   // 98304 B
    float lg[TPB][E_NUM + 1];             // stride 65 breaks phase-2 conflicts
  } u;

  const int tid  = threadIdx.x;
  const int tok0 = blockIdx.x * TPB;
  const int lane = tid & 63;
  const int wid  = tid >> 6;
  const int wm   = wid >> 1;              // token half  (32 tokens)
  const int wn   = wid & 1;               // expert half (32 experts)
  const int l31  = lane & 31;
  const int arow = 32 * wm + l31;         // token row for A frags
  const int brow = 32 * wn + l31;         // expert row for B frags
  const int kloff = 16 * (lane >> 5);     // byte offset of this lane's k-group

  const float* xg = x + (size_t)tok0 * H_DIM;

  // swizzled LDS byte address for (array, buf, row, kbyte)
  auto sw = [&](int arr, int b, int row, int kbyte) -> void* {
    return (char*)(&u.tiles[b][arr][0][0]) +
           row * 128 + (kbyte ^ ((row & 7) << 4));
  };

  float4 xr[4], wr[4];

  // 64 rows x 64 k fp32 tile each for x and W: 1024 float4 / 256 threads = 4.
  // row = f4>>4, kq = f4&15 -> 16 lanes read 256 B contiguous per row group.
  auto gload = [&](int kb) {
#pragma unroll
    for (int p = 0; p < 4; ++p) {
      const int f4  = tid + 256 * p;
      const int row = f4 >> 4;
      const int kq  = f4 & 15;
      xr[p] = *(const float4*)(xg + (size_t)row * H_DIM + kb + 4 * kq);
      wr[p] = *(const float4*)(W  + (size_t)row * H_DIM + kb + 4 * kq);
    }
  };

  // split fp32x4 -> 3x bf16x4 and store as swizzled b64 writes
  auto cvt_store = [&](const float4& v, int abase, int b, int row, int kbyte) {
    const float f[4] = {v.x, v.y, v.z, v.w};
    unsigned short h[4], m[4], l[4];
#pragma unroll
    for (int i = 0; i < 4; ++i) {
      float r1, r2;
      h[i] = bf_split(f[i], r1);
      m[i] = bf_split(r1, r2);
      l[i] = bf_rne(r2);
    }
    ushort4 hv = {h[0], h[1], h[2], h[3]};
    ushort4 mv = {m[0], m[1], m[2], m[3]};
    ushort4 lv = {l[0], l[1], l[2], l[3]};
    *(ushort4*)sw(abase + 0, b, row, kbyte) = hv;
    *(ushort4*)sw(abase + 1, b, row, kbyte) = mv;
    *(ushort4*)sw(abase + 2, b, row, kbyte) = lv;
  };

  auto sstore = [&](int b) {
#pragma unroll
    for (int p = 0; p < 4; ++p) {
      const int f4    = tid + 256 * p;
      const int row   = f4 >> 4;
      const int kbyte = (f4 & 15) * 8;    // 4 bf16 = 8 B per group
      cvt_store(xr[p], XH, b, row, kbyte);
      cvt_store(wr[p], WH, b, row, kbyte);
    }
  };

  gload(0);
  sstore(0);
  __syncthreads();

  // Two interleaved fp32 acc chains (halves MFMA dep latency; 48-add chains),
  // folded to fp64 every 4 chunks (256 k) -> ~2e-7 error class.
  f32x16 accA, accB;
  double accd[16];
#pragma unroll
  for (int r = 0; r < 16; ++r) { accA[r] = 0.f; accB[r] = 0.f; accd[r] = 0.0; }

  for (int c = 0; c < NCHUNK; ++c) {
    if (c + 1 < NCHUNK) gload((c + 1) * KC);   // prefetch next chunk to regs
    const int b = c & 1;

#pragma unroll
    for (int kt = 0; kt < 4; ++kt) {           // 4 k-tiles of 16 per chunk
      const int kb = kt * 32 + kloff;
      const short8 ah = *(const short8*)sw(XH, b, arow, kb);
      const short8 am = *(const short8*)sw(XM, b, arow, kb);
      const short8 al = *(const short8*)sw(XL, b, arow, kb);
      const short8 bh = *(const short8*)sw(WH, b, brow, kb);
      const short8 bm = *(const short8*)sw(WM, b, brow, kb);
      const short8 bl = *(const short8*)sw(WL, b, brow, kb);
      accA = __builtin_amdgcn_mfma_f32_32x32x16_bf16(ah, bh, accA, 0, 0, 0);
      accB = __builtin_amdgcn_mfma_f32_32x32x16_bf16(am, bm, accB, 0, 0, 0);
      accA = __builtin_amdgcn_mfma_f32_32x32x16_bf16(am, bh, accA, 0, 0, 0);
      accB = __builtin_amdgcn_mfma_f32_32x32x16_bf16(ah, bm, accB, 0, 0, 0);
      accA = __builtin_amdgcn_mfma_f32_32x32x16_bf16(al, bh, accA, 0, 0, 0);
      accB = __builtin_amdgcn_mfma_f32_32x32x16_bf16(ah, bl, accB, 0, 0, 0);
    }

    if ((c & 3) == 3) {    // fp64 fold every 4 chunks
#pragma unroll
      for (int r = 0; r < 16; ++r) {
        accd[r] += (double)accA[r] + (double)accB[r];
        accA[r] = 0.f; accB[r] = 0.f;
      }
    }

    if (c + 1 < NCHUNK) {
      // writes target buffer (c+1)&1 whose last readers finished before the
      // barrier that ended iteration c-1 -> one barrier per chunk suffices.
      sstore((c + 1) & 1);
      __syncthreads();
    }
  }

  __syncthreads();   // all frag reads done before lg overlays the tiles

  // C/D layout (HW-verified m74/m101): col = lane&31,
  // row = (reg&3) + 8*(reg>>2) + 4*(lane>>5).
  const int rb = 4 * (lane >> 5);
  float* gate = out + OFF_GATE;
#pragma unroll
  for (int q = 0; q < 4; ++q)
#pragma unroll
    for (int j = 0; j < 4; ++j) {
      const int reg   = 4 * q + j;
      const int row32 = j + 8 * q + rb;
      const float v   = (float)accd[reg];
      const int trow  = 32 * wm + row32;
      const int e     = 32 * wn + l31;
      gate[(size_t)(tok0 + trow) * E_NUM + e] = v;   // coalesced 128B/half-wave
      u.lg[trow][e] = v;
    }
  __syncthreads();

  // Phase 2: one thread per token (wave 0 only) — verbatim from the verified
  // kernel (strict > == jax lowest-index tie-break).
  if (tid < TPB) {
    const int t = tid;
    float vals[TOPK];
    int   idxs[TOPK];
#pragma unroll
    for (int p = 0; p < TOPK; ++p) {
      float best = -INFINITY;
      int   bi   = 0;
      for (int e = 0; e < E_NUM; ++e) {
        const float v = u.lg[t][e];
        if (v > best) { best = v; bi = e; }
      }
      vals[p] = best;
      idxs[p] = bi;
      u.lg[t][bi] = -INFINITY;
    }
    const float m = vals[0];
    float s = 0.f, pr[TOPK];
#pragma unroll
    for (int p = 0; p < TOPK; ++p) { pr[p] = __expf(vals[p] - m); s += pr[p]; }
    const float inv = 1.0f / s;
    for (int e = 0; e < E_NUM; ++e) u.lg[t][e] = 0.f;
#pragma unroll
    for (int p = 0; p < TOPK; ++p) u.lg[t][idxs[p]] = pr[p] * inv;

    float* oidx = out + OFF_IDX + (size_t)(tok0 + t) * TOPK;
#pragma unroll
    for (int p = 0; p < TOPK; ++p) oidx[p] = (float)idxs[p];
  }
  __syncthreads();

  // coalesced writeback of the sparse_probs rows
  float* oprob = out + (size_t)tok0 * E_NUM;
#pragma unroll
  for (int p = 0; p < 16; ++p) {
    const int f = tid + 256 * p;
    oprob[f] = u.lg[f >> 6][f & 63];
  }
}

extern "C" void kernel_launch(void* const* d_in, const int* in_sizes, int n_in,
                              void* d_out, int out_size, void* d_ws, size_t ws_size,
                              hipStream_t stream) {
  const float* x = (const float*)d_in[0];
  const float* W = (const float*)d_in[1];
  float* out = (float*)d_out;
  dim3 grid(N_TOK / TPB);   // 256 blocks -> 1 per CU
  dim3 block(256);          // 4 waves: (token-half, expert-half)
  gating_kernel<<<grid, block, 0, stream>>>(x, W, out);
}